// Round 1
// 108.403 us; speedup vs baseline: 1.1295x; 1.1295x over previous
//
#include <hip/hip_runtime.h>
#include <hip/hip_fp16.h>
#include <array>

// Problem constants (reference: H=64, M=N=128, k=9, w=3)
constexpr int HZ   = 64;
constexpr int NN   = 128;
constexpr int P    = HZ * NN * NN;    // 1,048,576 voxels
constexpr int KSEL = 9;
constexpr int NCOL = 27;              // 3x3x3 window

typedef _Float16 f16x2 __attribute__((ext_vector_type(2)));

constexpr int TY = 10;   // 8 core + 2 halo
constexpr int TX = 34;   // 32 core + 2 halo
constexpr int TROWS = 3 * TY * TX;   // 1020 tile rows (3 z-planes)

// ---------------------------------------------------------------------------
// Batcher merge-exchange network for n=27 + backward dead-CE pruning.
// ---------------------------------------------------------------------------
constexpr int compute_nce(int n) {
  int t = 0; while ((1 << t) < n) ++t;
  int cnt = 0;
  for (int p = 1 << (t - 1); p > 0; p >>= 1) {
    int q = 1 << (t - 1), r = 0, d = p;
    while (true) {
      for (int i = 0; i < n - d; ++i)
        if ((i & p) == r) ++cnt;
      if (q == p) break;
      d = q - p; r = p; q >>= 1;
    }
  }
  return cnt;
}
constexpr int NCE_FULL = compute_nce(NCOL);   // 155

struct CEPair { unsigned char a, b; };
constexpr std::array<CEPair, NCE_FULL> make_net() {
  std::array<CEPair, NCE_FULL> net{};
  int t = 0; while ((1 << t) < NCOL) ++t;
  int k = 0;
  for (int p = 1 << (t - 1); p > 0; p >>= 1) {
    int q = 1 << (t - 1), r = 0, d = p;
    while (true) {
      for (int i = 0; i < NCOL - d; ++i)
        if ((i & p) == r) {
          net[k].a = (unsigned char)i;
          net[k].b = (unsigned char)(i + d);
          ++k;
        }
      if (q == p) break;
      d = q - p; r = p; q >>= 1;
    }
  }
  return net;
}
constexpr auto FULLNET = make_net();

constexpr int count_pruned() {
  bool needed[NCOL] = {};
  for (int i = 0; i < KSEL; ++i) needed[i] = true;
  int cnt = 0;
  for (int e = NCE_FULL - 1; e >= 0; --e) {
    const int a = FULLNET[e].a, b = FULLNET[e].b;
    if (needed[a] || needed[b]) { needed[a] = true; needed[b] = true; ++cnt; }
  }
  return cnt;
}
constexpr int NCE = count_pruned();

constexpr std::array<CEPair, NCE> make_pruned() {
  bool needed[NCOL] = {};
  for (int i = 0; i < KSEL; ++i) needed[i] = true;
  std::array<bool, NCE_FULL> keep{};
  for (int e = NCE_FULL - 1; e >= 0; --e) {
    const int a = FULLNET[e].a, b = FULLNET[e].b;
    if (needed[a] || needed[b]) { keep[e] = true; needed[a] = true; needed[b] = true; }
  }
  std::array<CEPair, NCE> out{};
  int k = 0;
  for (int e = 0; e < NCE_FULL; ++e) if (keep[e]) out[k++] = FULLNET[e];
  return out;
}
constexpr auto NET = make_pruned();

// ---------------------------------------------------------------------------
// Async global->LDS DMA helpers (size must be a literal; LDS dest must be
// wave-uniform base + lane*size, which q = s*256+tid layouts satisfy).
// ---------------------------------------------------------------------------
typedef const __attribute__((address_space(1))) unsigned GU;
typedef __attribute__((address_space(3))) unsigned LU;

__device__ __forceinline__ void g2l16(const void* g, void* l) {
  __builtin_amdgcn_global_load_lds((GU*)g, (LU*)l, 16, 0, 0);
}
__device__ __forceinline__ void g2l4(const void* g, void* l) {
  __builtin_amdgcn_global_load_lds((GU*)g, (LU*)l, 4, 0, 0);
}

// ---------------------------------------------------------------------------
// Pass 1: key = db<<32 | col<<27 | vbits>>5 (63 bits, sign bit 0).
// IEEE order == unsigned order for non-negative doubles, so each CE is
// v_min_f64 + v_max_f64. Order = (db, col) exactly -> exact stable order.
// Row output (SoA, 24 B/voxel total):
//   rowsA[vb]  = uint4  : halves h0..h7
//   rowsB0[vb] = unsigned: h8 | (hi_cols15 << 16)   (cols 6..8, 5b each)
//   rowsB1[vb] = unsigned: lo_cols30                 (cols 0..5, 5b each)
// Direct per-thread stores are fully coalesced (lane-consecutive voxels),
// so no LDS store staging is needed.
// ---------------------------------------------------------------------------
__global__ __launch_bounds__(256) void topk9(
    const float* __restrict__ anat,
    uint4* __restrict__ rowsA,
    unsigned* __restrict__ rowsB0,
    unsigned* __restrict__ rowsB1) {
  __shared__ float in_t[TROWS];   // 4.08 KB input halo
  const int tid = threadIdx.x;

  const int blk = blockIdx.x;
  const int swz = ((blk & 7) << 9) | (blk >> 3);   // 8 XCDs x 512-slab
  const int z    = swz >> 6;
  const int rest = swz & 63;
  const int y0   = ((rest >> 2) & 15) << 3;
  const int x0   = (rest & 3) << 5;
  const int xl   = tid & 31;
  const int yl   = tid >> 5;

  #pragma unroll
  for (int s = 0; s < 4; ++s) {
    const unsigned q = (unsigned)(s * 256 + tid);
    if (q < (unsigned)TROWS) {
      const unsigned p = q / TX;
      const unsigned r = q - p * TX;
      const unsigned pz = p / TY;
      const int zi = (int)pz, yi = (int)(p - TY * pz);
      const int zz = (z + zi - 1) & (HZ - 1);
      const int yy = (y0 + yi - 1) & (NN - 1);
      const int xg = (x0 - 1 + (int)r) & (NN - 1);
      g2l4(&anat[(zz << 14) | (yy << 7) | xg], &in_t[q]);
    }
  }
  __syncthreads();

  const int base = (yl * TX) + xl;
  const float center = in_t[base + 1 * (TY * TX) + 1 * TX + 1];

  unsigned long long key[NCOL];
  #pragma unroll
  for (int c = 0; c < NCOL; ++c) {
    const int czi = c / 9, cyi = (c / 3) % 3, cxi = c % 3;
    const float v = in_t[base + czi * (TY * TX) + cyi * TX + cxi];
    const unsigned vb = __float_as_uint(v);
    const unsigned db = __float_as_uint(v - center) & 0x7fffffffu;
    const unsigned lo32 = ((unsigned)c << 27) | (vb >> 5);
    key[c] = ((unsigned long long)db << 32) | lo32;
  }

  // Pruned sorting network; CE = f64 min/max pair.
  #pragma unroll
  for (int e = 0; e < NCE; ++e) {
    const int a = NET[e].a, b = NET[e].b;
    const double ka = __builtin_bit_cast(double, key[a]);
    const double kb = __builtin_bit_cast(double, key[b]);
    key[a] = __builtin_bit_cast(unsigned long long, fmin(ka, kb));
    key[b] = __builtin_bit_cast(unsigned long long, fmax(ka, kb));
  }

  // Epilogue: col at [31:27] of low dword, value top-27 bits at [26:0].
  unsigned od[4] = {0, 0, 0, 0};
  unsigned h8 = 0, lo = 0, hi = 0;
  #pragma unroll
  for (int s = 0; s < KSEL; ++s) {
    const unsigned kl = (unsigned)key[s];
    const unsigned c  = (kl >> 27) & 31u;
    const unsigned vbits = (kl & 0x07ffffffu) << 5;
    const unsigned hb = (unsigned)__half_as_ushort(__float2half(__uint_as_float(vbits)));
    if (s < 8) od[s >> 1] |= hb << ((s & 1) * 16);
    else       h8 = hb;
    if (s < 6) lo |= c << (5 * s);
    else       hi |= c << (5 * (s - 6));
  }

  const unsigned vb = (unsigned)((z << 14) | ((y0 + yl) << 7) | (x0 + xl));
  rowsA[vb]  = make_uint4(od[0], od[1], od[2], od[3]);
  rowsB0[vb] = h8 | (hi << 16);
  rowsB1[vb] = lo;
}

// ---------------------------------------------------------------------------
// Pass 2: stage rowsA (16B/row) + rowsB0 (4B/row) halo tiles via
// global_load_lds; own lo-cols word comes straight from global (coalesced).
// Neighbor read = ds_read_b128 + ds_read_b32 (stride-4B -> conflict-free).
// LDS 20.4 KB/block; __launch_bounds__(256,5) targets >=20 waves/CU.
// ---------------------------------------------------------------------------
__global__ __launch_bounds__(256, 5) void weights9(
    const uint4* __restrict__ rowsA,
    const unsigned* __restrict__ rowsB0,
    const unsigned* __restrict__ rowsB1,
    const float* __restrict__ ksig,
    float* __restrict__ out) {
  __shared__ unsigned tile[TROWS * 5];     // tA: TROWS*4 dw, tB0: TROWS dw = 20400 B
  unsigned* tA  = tile;
  unsigned* tB0 = tile + TROWS * 4;
  const int tid = threadIdx.x;

  const int blk = blockIdx.x;
  const int swz = ((blk & 7) << 9) | (blk >> 3);
  const int z    = swz >> 6;
  const int rest = swz & 63;
  const int y0   = ((rest >> 2) & 15) << 3;
  const int x0   = (rest & 3) << 5;
  const int xl   = tid & 31;
  const int yl   = tid >> 5;

  const unsigned vb_own = (unsigned)((z << 14) | ((y0 + yl) << 7) | (x0 + xl));
  const unsigned lo = rowsB1[vb_own];      // own low-6 cols, coalesced dword

  #pragma unroll
  for (int s = 0; s < 4; ++s) {
    const unsigned q = (unsigned)(s * 256 + tid);
    if (q < (unsigned)TROWS) {
      const unsigned p = q / TX;
      const unsigned r = q - p * TX;
      const unsigned pz = p / TY;
      const int zi = (int)pz, yi = (int)(p - TY * pz);
      const int zz = (z + zi - 1) & (HZ - 1);
      const int yy = (y0 + yi - 1) & (NN - 1);
      const int xg = (x0 - 1 + (int)r) & (NN - 1);
      const unsigned vb = (unsigned)((zz << 14) | (yy << 7) | xg);
      g2l16(&rowsA[vb],  &tA[q * 4]);
      g2l4 (&rowsB0[vb], &tB0[q]);
    }
  }
  __syncthreads();

  // Own row.
  const int rho_own = (TY + (yl + 1)) * TX + (xl + 1);
  const uint4 a = *(const uint4*)&tA[rho_own * 4];
  const unsigned b0 = tB0[rho_own];
  f16x2 wh[5];
  wh[0] = __builtin_bit_cast(f16x2, a.x);
  wh[1] = __builtin_bit_cast(f16x2, a.y);
  wh[2] = __builtin_bit_cast(f16x2, a.z);
  wh[3] = __builtin_bit_cast(f16x2, a.w);
  wh[4] = __builtin_bit_cast(f16x2, b0 & 0xffffu);   // pad half = 0
  const unsigned hi = b0 >> 16;

  // Decode all 9 neighbor tile addresses, then batch-issue all 18 reads.
  int rho[KSEL];
  #pragma unroll
  for (int j = 0; j < KSEL; ++j) {
    const unsigned c = (j < 6) ? ((lo >> (5 * j)) & 31u)
                               : ((hi >> (5 * (j - 6))) & 31u);
    const unsigned czi = (c * 57u) >> 9;
    const unsigned rem = c - 9u * czi;
    const unsigned cyi = (rem * 11u) >> 5;
    const unsigned cxi = rem - 3u * cyi;
    rho[j] = (int)czi * (TY * TX) + (yl + (int)cyi) * TX + (xl + (int)cxi);
  }
  uint4 na[KSEL];
  unsigned nb[KSEL];
  #pragma unroll
  for (int j = 0; j < KSEL; ++j) {
    na[j] = *(const uint4*)&tA[rho[j] * 4];
    nb[j] = tB0[rho[j]];
  }

  // sigma with ddof=1 (two-pass, matches jnp.std).
  float ws[KSEL];
  #pragma unroll
  for (int l = 0; l < KSEL; ++l) ws[l] = (float)wh[l >> 1][l & 1];
  float mean = 0.f;
  #pragma unroll
  for (int l = 0; l < KSEL; ++l) mean += ws[l];
  mean *= (1.0f / 9.0f);
  float var = 0.f;
  #pragma unroll
  for (int l = 0; l < KSEL; ++l) { const float t = ws[l] - mean; var += t * t; }
  var *= (1.0f / 8.0f);
  const float sigma = sqrtf(var);

  const float ks = ksig[0];
  const float inv = (sigma == 0.f) ? 0.f : 1.0f / (2.0f * ks * ks * sigma * sigma);

  const _Float16 epsh = (_Float16)1e-6f;
  const f16x2 eps2 = {epsh, epsh};

  float logit[KSEL];
  #pragma unroll
  for (int j = 0; j < KSEL; ++j) {
    const f16x2 nh0 = __builtin_bit_cast(f16x2, na[j].x);
    const f16x2 nh1 = __builtin_bit_cast(f16x2, na[j].y);
    const f16x2 nh2 = __builtin_bit_cast(f16x2, na[j].z);
    const f16x2 nh3 = __builtin_bit_cast(f16x2, na[j].w);
    const f16x2 nh4 = __builtin_bit_cast(f16x2, nb[j] & 0xffffu);
    float s = 0.f;
    f16x2 dd;
    dd = (wh[0] - nh0) + eps2; s = __builtin_amdgcn_fdot2(dd, dd, s, false);
    dd = (wh[1] - nh1) + eps2; s = __builtin_amdgcn_fdot2(dd, dd, s, false);
    dd = (wh[2] - nh2) + eps2; s = __builtin_amdgcn_fdot2(dd, dd, s, false);
    dd = (wh[3] - nh3) + eps2; s = __builtin_amdgcn_fdot2(dd, dd, s, false);
    dd = (wh[4] - nh4) + eps2; s = __builtin_amdgcn_fdot2(dd, dd, s, false);
    logit[j] = -s * inv;
  }

  // softmax over the 9 logits
  float mx = logit[0];
  #pragma unroll
  for (int j = 1; j < KSEL; ++j) mx = fmaxf(mx, logit[j]);
  float sum = 0.f;
  float e[KSEL];
  #pragma unroll
  for (int j = 0; j < KSEL; ++j) { e[j] = __expf(logit[j] - mx); sum += e[j]; }
  const float rs = 1.0f / sum;

  // Output staging through LDS -> coalesced float4 stores.
  __syncthreads();
  float* tf = (float*)tile;
  #pragma unroll
  for (int j = 0; j < KSEL; ++j) tf[tid * KSEL + j] = e[j] * rs;
  __syncthreads();

  const float4* tf4 = (const float4*)tile;
  #pragma unroll
  for (int s = 0; s < 3; ++s) {
    const unsigned q = (unsigned)(s * 256 + tid);
    if (q < 576u) {
      const unsigned row = q / 72u;
      const unsigned f   = q - row * 72u;
      const unsigned vb  = (unsigned)((z << 14) | ((y0 + (int)row) << 7) | x0);
      ((float4*)out)[(size_t)(vb >> 2) * 9 + f] = tf4[row * 72 + f];
    }
  }
}

// ---------------------------------------------------------------------------
// d_in: [0] input (P floats), [1] ksigma (1 float), [2] k (int), [3] w (int)
// d_ws: rowsA (16 MB) + rowsB0 (4 MB) + rowsB1 (4 MB) = 24 MB
// ---------------------------------------------------------------------------
extern "C" void kernel_launch(void* const* d_in, const int* in_sizes, int n_in,
                              void* d_out, int out_size, void* d_ws, size_t ws_size,
                              hipStream_t stream) {
  const float* anat = (const float*)d_in[0];
  const float* ksig = (const float*)d_in[1];
  uint4* rowsA      = (uint4*)d_ws;
  unsigned* rowsB0  = (unsigned*)d_ws + (size_t)4 * P;
  unsigned* rowsB1  = rowsB0 + P;

  const int blocks = P / 256;
  topk9<<<blocks, 256, 0, stream>>>(anat, rowsA, rowsB0, rowsB1);
  weights9<<<blocks, 256, 0, stream>>>(rowsA, rowsB0, rowsB1, ksig, (float*)d_out);
}